// Round 14
// baseline (55.194 us; speedup 1.0000x reference)
//
#include <hip/hip_runtime.h>
#include <stdint.h>

// Problem constants
#define B_ 131072
#define T_ 8
#define C_ 32
#define H_ 4
#define D_ 8

#define NT 4      // tiles per wave
// per-wave HALF-slab: Q f16 fpair-packed [16 rows][18 dw] = 1152 B
//                     K_T f16 [32 rows][32 B] = 1024 B; V_T same = 1024 B
#define QOFF 0
#define KOFF 1152
#define VOFF 2176
#define HSLAB 3200
// double-buffered: 2*HSLAB per wave -> 25600 B/block

typedef _Float16 h16x2 __attribute__((ext_vector_type(2)));
typedef _Float16 f16x8 __attribute__((ext_vector_type(8)));
typedef float    f32x4 __attribute__((ext_vector_type(4)));
typedef __fp16   fp16x2 __attribute__((ext_vector_type(2)));  // cvt_pkrtz ret

union H2U { fp16x2 h; uint32_t u; };
union HW  { uint32_t u; h16x2 h; };
union F8U { f16x8 v; uint32_t u[4]; };
union V4  { uint4 u; h16x2 h2[4]; };

__device__ inline uint32_t pk(float lo, float hi) {
    H2U t; t.h = __builtin_amdgcn_cvt_pkrtz(lo, hi); return t.u;
}
__device__ inline h16x2 bch(uint32_t x) { HW t; t.u = x; return t.h; }

struct X2 { float4 a, b; };

// R13 components (proven): Q f16 fpair-packed, K/V feature-major bijective
// permute, no-max softmax, deferred winv. NEW: 2-deep attention pipeline —
// attn2() runs TWO independent tiles' attention in one straight-line block
// (shared K/V address calc, duplicated state) so every latency stall of one
// chain is filled by the other. Schedule: stage-pair -> attn2 -> stage-pair
// -> attn2 (stage pairs expose 12 independent MFMAs similarly).
// LDS wave-private: no barriers.
__global__ __launch_bounds__(256, 4) void attn_block_mfma(
    const float* __restrict__ X,
    const float* __restrict__ Wq,
    const float* __restrict__ Wk,
    const float* __restrict__ Wv,
    const float* __restrict__ Wf,
    const float* __restrict__ bfb,
    float* __restrict__ Y)
{
    __shared__ __align__(16) char ldsraw[4][2][HSLAB];
    const int wid  = threadIdx.x >> 6;
    const int lane = threadIdx.x & 63;
    const int cc = lane & 15;   // C-frag col; attention row t
    const int gg = lane >> 4;   // k-group; attention head
    char* base = &ldsraw[wid][0][0];

    // 1/sqrt(D) * log2(e): exp(x) = exp2(x*log2e), folded into Wq
    const float qscale = 0.35355339059327373f * 1.4426950408889634f;

    // ---------- preamble: weight B-frags (f16) ----------
    f16x8 bW[6];   // 0,1=q  2,3=k  4,5=v   (B-frag: col=lane&15, k=gg*8+j)
    {
        const float* const Ws[3] = { Wq, Wk, Wv };
        #pragma unroll
        for (int tau = 0; tau < 6; ++tau) {
            const float* Wm = Ws[tau >> 1];
            const int col = (tau & 1) * 16 + cc;
            const int head = col >> 3, d = col & 7;
            #pragma unroll
            for (int j = 0; j < 8; ++j) {
                float f = Wm[head * (C_ * D_) + (gg * 8 + j) * D_ + d];
                if (tau < 2) f *= qscale;
                bW[tau][j] = (_Float16)f;
            }
        }
    }
    f16x8 bF[2];   // FF weights
    {
        #pragma unroll
        for (int tau = 0; tau < 2; ++tau) {
            const int col = tau * 16 + cc;
            #pragma unroll
            for (int j = 0; j < 8; ++j)
                bF[tau][j] = (_Float16)Wf[(gg * 8 + j) * C_ + col];
        }
    }
    const float bias0 = bfb[cc];
    const float bias1 = bfb[cc + 16];

    const int tilebase = (blockIdx.x * 4 + wid) * (16 * NT);
    const f32x4 z = { 0.f, 0.f, 0.f, 0.f };
    const int tpos = cc & 7, bb = cc >> 3;

    auto ldx = [&](int it) {
        const float* p = X + (size_t)(tilebase + it * 16 + cc) * C_ + gg * 8;
        X2 r; r.a = *(const float4*)p; r.b = *(const float4*)(p + 4); return r;
    };

    // stage: QKV projection for one tile into slab `slot` (R13-exact)
    auto stage = [&](int slot, X2 x) {
        f16x8 aX;   // A-frag from X: row = lane&15, k = gg*8+j
        aX[0] = (_Float16)x.a.x; aX[1] = (_Float16)x.a.y;
        aX[2] = (_Float16)x.a.z; aX[3] = (_Float16)x.a.w;
        aX[4] = (_Float16)x.b.x; aX[5] = (_Float16)x.b.y;
        aX[6] = (_Float16)x.b.z; aX[7] = (_Float16)x.b.w;

        f32x4 cq[6];
        #pragma unroll
        for (int tau = 0; tau < 6; ++tau)
            cq[tau] = __builtin_amdgcn_mfma_f32_16x16x32_f16(aX, bW[tau], z, 0, 0, 0);

        char* b2 = base + slot * HSLAB;
        uint32_t* qb = (uint32_t*)(b2 + QOFF);
        // Q -> fpair dwords (q[t][cc], q[t][cc+16]), rows gg*4+r, stride 18 dw
        #pragma unroll
        for (int r = 0; r < 4; ++r)
            qb[(gg * 4 + r) * 18 + cc] = pk(cq[0][r], cq[1][r]);
        // K,V -> packed f16 feature-major; row p = (cc&3)*8+(tau&1)*4+(cc>>2)
        #pragma unroll
        for (int tau = 2; tau < 6; ++tau) {
            char* dst = b2 + ((tau < 4) ? KOFF : VOFF);
            const int p = (cc & 3) * 8 + (tau & 1) * 4 + (cc >> 2);
            uint2 w2;
            w2.x = pk(cq[tau][0], cq[tau][1]);
            w2.y = pk(cq[tau][2], cq[tau][3]);
            *(uint2*)(dst + p * 32 + gg * 8) = w2;
        }
    };

    // attn2: attention + FF + store for TWO tiles (independent chains,
    // shared K/V address calc) — the 2-deep ILP pipeline.
    auto attn2 = [&](int slot_a, int it_a, int slot_b, int it_b) {
        char* ba = base + slot_a * HSLAB;
        char* bbse = base + slot_b * HSLAB;
        const char* kba = ba + KOFF;
        const char* vba = ba + VOFF;
        const char* kbb = bbse + KOFF;
        const char* vbb = bbse + VOFF;

        // ---- Q reads (both) ----
        V4 qa0, qa1, qb0, qb1;
        {
            const char* qaa = ba + QOFF;
            const char* qbb2 = bbse + QOFF;
            const int qoff = cc * 72 + (gg & 1) * 32;
            qa0.u = *(const uint4*)(qaa + qoff);
            qa1.u = *(const uint4*)(qaa + qoff + 16);
            qb0.u = *(const uint4*)(qbb2 + qoff);
            qb1.u = *(const uint4*)(qbb2 + qoff + 16);
        }
        const bool hi = gg >= 2;
        h16x2 qja[8], qjb[8];
        #pragma unroll
        for (int j = 0; j < 4; ++j) {
            const _Float16 a0 = hi ? qa0.h2[j][1] : qa0.h2[j][0];
            const _Float16 a1 = hi ? qa1.h2[j][1] : qa1.h2[j][0];
            const _Float16 b0 = hi ? qb0.h2[j][1] : qb0.h2[j][0];
            const _Float16 b1 = hi ? qb1.h2[j][1] : qb1.h2[j][0];
            qja[j]     = h16x2{ a0, a0 };
            qja[j + 4] = h16x2{ a1, a1 };
            qjb[j]     = h16x2{ b0, b0 };
            qjb[j + 4] = h16x2{ b1, b1 };
        }

        // ---- scores (both, shared p addressing) ----
        h16x2 sa01 = { (_Float16)0, (_Float16)0 };
        h16x2 sa23 = sa01, sa45 = sa01, sa67 = sa01;
        h16x2 sb01 = sa01, sb23 = sa01, sb45 = sa01, sb67 = sa01;
        #pragma unroll
        for (int j = 0; j < 8; ++j) {
            const int off = (((j & 3) << 3) | (gg * 2) | (j >> 2)) * 32 + bb * 16;
            const uint4 kua = *(const uint4*)(kba + off);
            const uint4 kub = *(const uint4*)(kbb + off);
            sa01 += qja[j] * bch(kua.x);
            sb01 += qjb[j] * bch(kub.x);
            sa23 += qja[j] * bch(kua.y);
            sb23 += qjb[j] * bch(kub.y);
            sa45 += qja[j] * bch(kua.z);
            sb45 += qjb[j] * bch(kub.z);
            sa67 += qja[j] * bch(kua.w);
            sb67 += qjb[j] * bch(kub.w);
        }
        float sca[8], scb[8];
        sca[0] = (float)sa01[0]; sca[1] = (float)sa01[1];
        sca[2] = (float)sa23[0]; sca[3] = (float)sa23[1];
        sca[4] = (float)sa45[0]; sca[5] = (float)sa45[1];
        sca[6] = (float)sa67[0]; sca[7] = (float)sa67[1];
        scb[0] = (float)sb01[0]; scb[1] = (float)sb01[1];
        scb[2] = (float)sb23[0]; scb[3] = (float)sb23[1];
        scb[4] = (float)sb45[0]; scb[5] = (float)sb45[1];
        scb[6] = (float)sb67[0]; scb[7] = (float)sb67[1];
        #pragma unroll
        for (int s = 1; s < 8; ++s) {
            if (s > tpos) { sca[s] = -1.0e30f; scb[s] = -1.0e30f; }
        }

        // ---- no-max softmax (both); winv deferred past PV ----
        float ea[8], eb[8];
        #pragma unroll
        for (int s = 0; s < 8; ++s) { ea[s] = exp2f(sca[s]); eb[s] = exp2f(scb[s]); }
        const float suma = ((ea[0] + ea[1]) + (ea[2] + ea[3]))
                         + ((ea[4] + ea[5]) + (ea[6] + ea[7]));
        const float sumb = ((eb[0] + eb[1]) + (eb[2] + eb[3]))
                         + ((eb[4] + eb[5]) + (eb[6] + eb[7]));
        const float winva = 1.0f / suma;
        const float winvb = 1.0f / sumb;

        const h16x2 wa0 = bch(pk(ea[0], ea[1])), wa1 = bch(pk(ea[2], ea[3]));
        const h16x2 wa2 = bch(pk(ea[4], ea[5])), wa3 = bch(pk(ea[6], ea[7]));
        const h16x2 wb0 = bch(pk(eb[0], eb[1])), wb1 = bch(pk(eb[2], eb[3]));
        const h16x2 wb2 = bch(pk(eb[4], eb[5])), wb3 = bch(pk(eb[6], eb[7]));

        // ---- PV (both, shared p addressing) ----
        float oa[8], ob[8];
        #pragma unroll
        for (int d = 0; d < 8; ++d) {
            const int off = (((d & 3) << 3) | (gg * 2) | (d >> 2)) * 32 + bb * 16;
            const uint4 vua = *(const uint4*)(vba + off);
            const uint4 vub = *(const uint4*)(vbb + off);
            h16x2 acca = wa0 * bch(vua.x);
            h16x2 accb = wb0 * bch(vub.x);
            acca += wa1 * bch(vua.y);
            accb += wb1 * bch(vub.y);
            acca += wa2 * bch(vua.z);
            accb += wb2 * bch(vub.z);
            acca += wa3 * bch(vua.w);
            accb += wb3 * bch(vub.w);
            oa[d] = ((float)acca[0] + (float)acca[1]) * winva;
            ob[d] = ((float)accb[0] + (float)accb[1]) * winvb;
        }

        // ---- FF + stores (both) ----
        F8U aOa, aOb;
        aOa.u[0] = pk(oa[0], oa[1]); aOa.u[1] = pk(oa[2], oa[3]);
        aOa.u[2] = pk(oa[4], oa[5]); aOa.u[3] = pk(oa[6], oa[7]);
        aOb.u[0] = pk(ob[0], ob[1]); aOb.u[1] = pk(ob[2], ob[3]);
        aOb.u[2] = pk(ob[4], ob[5]); aOb.u[3] = pk(ob[6], ob[7]);

        const f32x4 ya0 = __builtin_amdgcn_mfma_f32_16x16x32_f16(aOa.v, bF[0], z, 0, 0, 0);
        const f32x4 ya1 = __builtin_amdgcn_mfma_f32_16x16x32_f16(aOa.v, bF[1], z, 0, 0, 0);
        const f32x4 yb0 = __builtin_amdgcn_mfma_f32_16x16x32_f16(aOb.v, bF[0], z, 0, 0, 0);
        const f32x4 yb1 = __builtin_amdgcn_mfma_f32_16x16x32_f16(aOb.v, bF[1], z, 0, 0, 0);

        const int rba = tilebase + it_a * 16;
        const int rbb = tilebase + it_b * 16;
        #pragma unroll
        for (int r = 0; r < 4; ++r) {
            float* ypa = Y + (size_t)(rba + gg * 4 + r) * C_;
            float* ypb = Y + (size_t)(rbb + gg * 4 + r) * C_;
            ypa[cc]      = fmaxf(ya0[r] + bias0, 0.f);
            ypa[cc + 16] = fmaxf(ya1[r] + bias1, 0.f);
            ypb[cc]      = fmaxf(yb0[r] + bias0, 0.f);
            ypb[cc + 16] = fmaxf(yb1[r] + bias1, 0.f);
        }
    };

    // ---- schedule: stage-pair -> attn2 -> stage-pair -> attn2 ----
    X2 x0 = ldx(0), x1 = ldx(1);
    stage(0, x0);
    stage(1, x1);
    X2 x2 = ldx(2), x3 = ldx(3);   // issue early: HBM hides under attn2 #1
    attn2(0, 0, 1, 1);
    stage(0, x2);
    stage(1, x3);
    attn2(0, 2, 1, 3);
}

extern "C" void kernel_launch(void* const* d_in, const int* in_sizes, int n_in,
                              void* d_out, int out_size, void* d_ws, size_t ws_size,
                              hipStream_t stream)
{
    const float* X  = (const float*)d_in[0];
    const float* Wq = (const float*)d_in[1];
    const float* Wk = (const float*)d_in[2];
    const float* Wv = (const float*)d_in[3];
    const float* Wf = (const float*)d_in[4];
    const float* bf = (const float*)d_in[5];
    float* Y = (float*)d_out;

    const int rows = B_ * T_;                 // 1,048,576
    const int rows_per_block = 4 * NT * 16;   // 256
    dim3 grid(rows / rows_per_block), block(256);
    hipLaunchKernelGGL(attn_block_mfma, grid, block, 0, stream,
                       X, Wq, Wk, Wv, Wf, bf, Y);
}

// Round 15
// 54.864 us; speedup vs baseline: 1.0060x; 1.0060x over previous
//
#include <hip/hip_runtime.h>
#include <stdint.h>

// Problem constants
#define B_ 131072
#define T_ 8
#define C_ 32
#define H_ 4
#define D_ 8
#define NT 4

typedef _Float16 f16x4 __attribute__((ext_vector_type(4)));
typedef _Float16 f16x8 __attribute__((ext_vector_type(8)));
typedef float    f32x4 __attribute__((ext_vector_type(4)));
typedef __fp16   fp16x2 __attribute__((ext_vector_type(2)));  // cvt_pkrtz ret

union H2U { fp16x2 h; uint32_t u; };
union F4U { f16x4 v; uint32_t u[2]; };

__device__ inline uint32_t pk(float lo, float hi) {
    H2U t; t.h = __builtin_amdgcn_cvt_pkrtz(lo, hi); return t.u;
}
__device__ inline f16x4 mk4(float a, float b, float c, float d) {
    F4U t; t.u[0] = pk(a, b); t.u[1] = pk(c, d); return t.v;
}

struct X2 { float4 a, b; };

// ZERO-LDS design: attention chained entirely through MFMA fragments.
// Identity used throughout: a 16x16 C-frag (col=lane&15, row=gg*4+r in regs)
// is bit-identical to a 16x16x16 A/B-frag (row/col=lane&15, k=gg*4+j)
// representing the TRANSPOSED matrix. Chain:
//   Q^T,K^T staged transposed (R6-proven), V normal (R13-proven)
//   S^T_h = mfma16(K^T-frag, Q^T-frag head-zeroed)   [f32-accum QK^T]
//   softmax in S^T layout (s in regs, t in lane): mask/exp per reg,
//     rowsum = 3 adds + shfl_xor(16) + shfl_xor(32); winv deferred
//   O^T_h = mfma16(V-frag, P_h)  -> gg-merge heads, scale by winv[t=lane]
//   Y^T  = mfma16(Wf^T, O^T) x4 (2 c-tiles x 2 k-tiles, C-chained)
//   bias+ReLU in regs; transpose back via mfma16(Y^T, I) -> coalesced store
__global__ __launch_bounds__(256, 4) void attn_block_mfma(
    const float* __restrict__ X,
    const float* __restrict__ Wq,
    const float* __restrict__ Wk,
    const float* __restrict__ Wv,
    const float* __restrict__ Wf,
    const float* __restrict__ bfb,
    float* __restrict__ Y)
{
    const int lane = threadIdx.x & 63;
    const int wid  = threadIdx.x >> 6;
    const int cc = lane & 15;
    const int gg = lane >> 4;

    // 1/sqrt(D) * log2(e): exp(x) = exp2(x*log2e), folded into Wq
    const float qscale = 0.35355339059327373f * 1.4426950408889634f;

    // ---------- preamble: weight fragments ----------
    // wQKV[0,1]=q^T-A  [2,3]=k^T-A  [4,5]=v-B : all share the same
    // (lane,reg)->(f,c) map (A[row=f][k=c] == B[k=c][col=f] register-wise).
    f16x8 wQKV[6];
    {
        const float* const Ws[3] = { Wq, Wk, Wv };
        #pragma unroll
        for (int tau = 0; tau < 6; ++tau) {
            const float* Wm = Ws[tau >> 1];
            const int f = (tau & 1) * 16 + cc;
            const int head = f >> 3, d = f & 7;
            #pragma unroll
            for (int j = 0; j < 8; ++j) {
                float v = Wm[head * (C_ * D_) + (gg * 8 + j) * D_ + d];
                if (tau < 2) v *= qscale;
                wQKV[tau][j] = (_Float16)v;
            }
        }
    }
    // Wf^T A-frags for 16x16x16: A[row=c=ct*16+cc][k=f=kt*16+gg*4+j]
    f16x4 aWf[2][2];
    #pragma unroll
    for (int ct = 0; ct < 2; ++ct)
        #pragma unroll
        for (int kt = 0; kt < 2; ++kt)
            #pragma unroll
            for (int j = 0; j < 4; ++j)
                aWf[ct][kt][j] = (_Float16)Wf[(kt * 16 + gg * 4 + j) * C_ + ct * 16 + cc];
    // identity B-frag: I[k=gg*4+j][col=cc]
    f16x4 If;
    #pragma unroll
    for (int j = 0; j < 4; ++j)
        If[j] = (_Float16)((gg * 4 + j == cc) ? 1.0f : 0.0f);
    // bias per FF reg c = ct*16 + gg*4 + r
    const float4 ba = *(const float4*)(bfb + gg * 4);
    const float4 bbb = *(const float4*)(bfb + 16 + gg * 4);

    const int tilebase = (blockIdx.x * 4 + wid) * (16 * NT);
    const f32x4 z = { 0.f, 0.f, 0.f, 0.f };
    const bool gglo = (gg < 2);
    const f16x4 zero4 = { (_Float16)0, (_Float16)0, (_Float16)0, (_Float16)0 };

    // mask precompute: t = cc; s = gg*4+r. valid = same-batch && s<=t
    bool vmask[4];
    {
        const bool sb = ((gg >> 1) == (cc >> 3));
        #pragma unroll
        for (int r = 0; r < 4; ++r)
            vmask[r] = sb && (gg * 4 + r <= cc);
    }

    // rolling X prefetch (1 tile ahead)
    X2 x;
    {
        const float* p = X + (size_t)(tilebase + cc) * C_ + gg * 8;
        x.a = *(const float4*)p; x.b = *(const float4*)(p + 4);
    }

    #pragma unroll 1
    for (int it = 0; it < NT; ++it) {
        X2 xn;
        {
            const int itn = (it + 1 < NT) ? it + 1 : it;
            const float* p = X + (size_t)(tilebase + itn * 16 + cc) * C_ + gg * 8;
            xn.a = *(const float4*)p; xn.b = *(const float4*)(p + 4);
        }

        // X^T/X frag (works as B for transposed stage AND A for normal stage)
        f16x8 aX;
        aX[0] = (_Float16)x.a.x; aX[1] = (_Float16)x.a.y;
        aX[2] = (_Float16)x.a.z; aX[3] = (_Float16)x.a.w;
        aX[4] = (_Float16)x.b.x; aX[5] = (_Float16)x.b.y;
        aX[6] = (_Float16)x.b.z; aX[7] = (_Float16)x.b.w;

        // ---- stage: Q^T,K^T transposed; V normal (6 MFMAs) ----
        const f32x4 cq0 = __builtin_amdgcn_mfma_f32_16x16x32_f16(wQKV[0], aX, z, 0, 0, 0);
        const f32x4 cq1 = __builtin_amdgcn_mfma_f32_16x16x32_f16(wQKV[1], aX, z, 0, 0, 0);
        const f32x4 ck0 = __builtin_amdgcn_mfma_f32_16x16x32_f16(wQKV[2], aX, z, 0, 0, 0);
        const f32x4 ck1 = __builtin_amdgcn_mfma_f32_16x16x32_f16(wQKV[3], aX, z, 0, 0, 0);
        const f32x4 cv0 = __builtin_amdgcn_mfma_f32_16x16x32_f16(aX, wQKV[4], z, 0, 0, 0);
        const f32x4 cv1 = __builtin_amdgcn_mfma_f32_16x16x32_f16(aX, wQKV[5], z, 0, 0, 0);

        // cvt C-frags -> f16 chaining frags
        const f16x4 qT0 = mk4(cq0[0], cq0[1], cq0[2], cq0[3]);
        const f16x4 qT1 = mk4(cq1[0], cq1[1], cq1[2], cq1[3]);
        const f16x4 kT0 = mk4(ck0[0], ck0[1], ck0[2], ck0[3]);
        const f16x4 kT1 = mk4(ck1[0], ck1[1], ck1[2], ck1[3]);
        const f16x4 vF0 = mk4(cv0[0], cv0[1], cv0[2], cv0[3]);
        const f16x4 vF1 = mk4(cv1[0], cv1[1], cv1[2], cv1[3]);

        // per-head zeroed Q^T (k-range select by gg)
        const f16x4 qh0 = gglo ? qT0 : zero4;
        const f16x4 qh1 = gglo ? zero4 : qT0;
        const f16x4 qh2 = gglo ? qT1 : zero4;
        const f16x4 qh3 = gglo ? zero4 : qT1;

        // ---- scores: S^T_h[s][t] (s in regs, t in lane) ----
        const f32x4 s0 = __builtin_amdgcn_mfma_f32_16x16x16f16(kT0, qh0, z, 0, 0, 0);
        const f32x4 s1 = __builtin_amdgcn_mfma_f32_16x16x16f16(kT0, qh1, z, 0, 0, 0);
        const f32x4 s2 = __builtin_amdgcn_mfma_f32_16x16x16f16(kT1, qh2, z, 0, 0, 0);
        const f32x4 s3 = __builtin_amdgcn_mfma_f32_16x16x16f16(kT1, qh3, z, 0, 0, 0);

        // ---- mask + exp (no-max: scores O(0.1)) ----
        float e0[4], e1[4], e2[4], e3[4];
        #pragma unroll
        for (int r = 0; r < 4; ++r) {
            e0[r] = vmask[r] ? exp2f(s0[r]) : 0.f;
            e1[r] = vmask[r] ? exp2f(s1[r]) : 0.f;
            e2[r] = vmask[r] ? exp2f(s2[r]) : 0.f;
            e3[r] = vmask[r] ? exp2f(s3[r]) : 0.f;
        }
        // rowsum over s: local + xor16 + xor32  -> every lane holds sum(t=cc,h)
        float p0 = (e0[0] + e0[1]) + (e0[2] + e0[3]);
        float p1 = (e1[0] + e1[1]) + (e1[2] + e1[3]);
        float p2 = (e2[0] + e2[1]) + (e2[2] + e2[3]);
        float p3 = (e3[0] + e3[1]) + (e3[2] + e3[3]);
        p0 += __shfl_xor(p0, 16); p1 += __shfl_xor(p1, 16);
        p2 += __shfl_xor(p2, 16); p3 += __shfl_xor(p3, 16);
        p0 += __shfl_xor(p0, 32); p1 += __shfl_xor(p1, 32);
        p2 += __shfl_xor(p2, 32); p3 += __shfl_xor(p3, 32);
        const float w0 = 1.0f / p0, w1 = 1.0f / p1;
        const float w2 = 1.0f / p2, w3 = 1.0f / p3;

        // P^T f16 B-frags (unnormalized)
        const f16x4 P0 = mk4(e0[0], e0[1], e0[2], e0[3]);
        const f16x4 P1 = mk4(e1[0], e1[1], e1[2], e1[3]);
        const f16x4 P2 = mk4(e2[0], e2[1], e2[2], e2[3]);
        const f16x4 P3 = mk4(e3[0], e3[1], e3[2], e3[3]);

        // ---- PV: O^T_h[f'][t] (f' in regs, t in lane) ----
        const f32x4 o0 = __builtin_amdgcn_mfma_f32_16x16x16f16(vF0, P0, z, 0, 0, 0);
        const f32x4 o1 = __builtin_amdgcn_mfma_f32_16x16x16f16(vF0, P1, z, 0, 0, 0);
        const f32x4 o2 = __builtin_amdgcn_mfma_f32_16x16x16f16(vF1, P2, z, 0, 0, 0);
        const f32x4 o3 = __builtin_amdgcn_mfma_f32_16x16x16f16(vF1, P3, z, 0, 0, 0);

        // merge heads (valid rows: h even -> gg<2, h odd -> gg>=2) + scale
        const float wa = gglo ? w0 : w1;
        const float wb = gglo ? w2 : w3;
        f16x4 Bm0, Bm1;
        #pragma unroll
        for (int r = 0; r < 4; r += 2) {
            const float a0 = (gglo ? o0[r]     : o1[r])     * wa;
            const float a1 = (gglo ? o0[r + 1] : o1[r + 1]) * wa;
            const float b0 = (gglo ? o2[r]     : o3[r])     * wb;
            const float b1 = (gglo ? o2[r + 1] : o3[r + 1]) * wb;
            F4U t0, t1;
            t0.u[0] = pk(a0, a1); t1.u[0] = pk(b0, b1);
            if (r == 0) { Bm0[0] = t0.v[0]; Bm0[1] = t0.v[1]; Bm1[0] = t1.v[0]; Bm1[1] = t1.v[1]; }
            else        { Bm0[2] = t0.v[0]; Bm0[3] = t0.v[1]; Bm1[2] = t1.v[0]; Bm1[3] = t1.v[1]; }
        }

        // ---- FF: Y^T[c][t] = Wf^T O^T (2 c-tiles x 2 k-tiles) ----
        f32x4 yT0 = __builtin_amdgcn_mfma_f32_16x16x16f16(aWf[0][0], Bm0, z, 0, 0, 0);
        yT0 = __builtin_amdgcn_mfma_f32_16x16x16f16(aWf[0][1], Bm1, yT0, 0, 0, 0);
        f32x4 yT1 = __builtin_amdgcn_mfma_f32_16x16x16f16(aWf[1][0], Bm0, z, 0, 0, 0);
        yT1 = __builtin_amdgcn_mfma_f32_16x16x16f16(aWf[1][1], Bm1, yT1, 0, 0, 0);

        // bias + ReLU in Y^T layout (bias is per-reg here), then -> f16
        const f16x4 yf0 = mk4(fmaxf(yT0[0] + ba.x, 0.f), fmaxf(yT0[1] + ba.y, 0.f),
                              fmaxf(yT0[2] + ba.z, 0.f), fmaxf(yT0[3] + ba.w, 0.f));
        const f16x4 yf1 = mk4(fmaxf(yT1[0] + bbb.x, 0.f), fmaxf(yT1[1] + bbb.y, 0.f),
                              fmaxf(yT1[2] + bbb.z, 0.f), fmaxf(yT1[3] + bbb.w, 0.f));

        // transpose back via identity: Y[t][c] (t in regs, c in lane)
        const f32x4 yn0 = __builtin_amdgcn_mfma_f32_16x16x16f16(yf0, If, z, 0, 0, 0);
        const f32x4 yn1 = __builtin_amdgcn_mfma_f32_16x16x16f16(yf1, If, z, 0, 0, 0);

        // coalesced store (R13-proven pattern)
        const int rowbase = tilebase + it * 16;
        #pragma unroll
        for (int r = 0; r < 4; ++r) {
            float* yp = Y + (size_t)(rowbase + gg * 4 + r) * C_;
            yp[cc]      = yn0[r];
            yp[cc + 16] = yn1[r];
        }

        x = xn;
    }
}

extern "C" void kernel_launch(void* const* d_in, const int* in_sizes, int n_in,
                              void* d_out, int out_size, void* d_ws, size_t ws_size,
                              hipStream_t stream)
{
    const float* X  = (const float*)d_in[0];
    const float* Wq = (const float*)d_in[1];
    const float* Wk = (const float*)d_in[2];
    const float* Wv = (const float*)d_in[3];
    const float* Wf = (const float*)d_in[4];
    const float* bf = (const float*)d_in[5];
    float* Y = (float*)d_out;

    const int rows = B_ * T_;                 // 1,048,576
    const int rows_per_block = 4 * NT * 16;   // 256
    dim3 grid(rows / rows_per_block), block(256);
    hipLaunchKernelGGL(attn_block_mfma, grid, block, 0, stream,
                       X, Wq, Wk, Wv, Wf, bf, Y);
}

// Round 16
// 52.708 us; speedup vs baseline: 1.0472x; 1.0409x over previous
//
#include <hip/hip_runtime.h>
#include <stdint.h>

// Problem constants
#define B_ 131072
#define T_ 8
#define C_ 32
#define H_ 4
#define D_ 8
#define NT 4

typedef _Float16 f16x4 __attribute__((ext_vector_type(4)));
typedef _Float16 f16x8 __attribute__((ext_vector_type(8)));
typedef float    f32x4 __attribute__((ext_vector_type(4)));
typedef __fp16   fp16x2 __attribute__((ext_vector_type(2)));  // cvt_pkrtz ret

union H2U { fp16x2 h; uint32_t u; };
union F4U { f16x4 v; uint32_t u[2]; };

__device__ inline uint32_t pk(float lo, float hi) {
    H2U t; t.h = __builtin_amdgcn_cvt_pkrtz(lo, hi); return t.u;
}
__device__ inline f16x4 mk4(float a, float b, float c, float d) {
    F4U t; t.u[0] = pk(a, b); t.u[1] = pk(c, d); return t.v;
}

struct X2 { float4 a, b; };

// R15 zero-LDS MFMA-chained kernel + ONE change: non-temporal Y stores.
// Rationale: X(128MiB)+Y(128MiB) = 256MiB = exactly L3; Y write-allocations
// evict X every replay (FETCH showed half of X re-fetched from HBM). Y is
// write-once-never-read -> `nt` stores keep it out of L2/L3, X becomes
// L3-resident, HBM traffic drops to ~writes-only.
__global__ __launch_bounds__(256, 4) void attn_block_mfma(
    const float* __restrict__ X,
    const float* __restrict__ Wq,
    const float* __restrict__ Wk,
    const float* __restrict__ Wv,
    const float* __restrict__ Wf,
    const float* __restrict__ bfb,
    float* __restrict__ Y)
{
    const int lane = threadIdx.x & 63;
    const int wid  = threadIdx.x >> 6;
    const int cc = lane & 15;
    const int gg = lane >> 4;

    // 1/sqrt(D) * log2(e): exp(x) = exp2(x*log2e), folded into Wq
    const float qscale = 0.35355339059327373f * 1.4426950408889634f;

    // ---------- preamble: weight fragments ----------
    f16x8 wQKV[6];
    {
        const float* const Ws[3] = { Wq, Wk, Wv };
        #pragma unroll
        for (int tau = 0; tau < 6; ++tau) {
            const float* Wm = Ws[tau >> 1];
            const int f = (tau & 1) * 16 + cc;
            const int head = f >> 3, d = f & 7;
            #pragma unroll
            for (int j = 0; j < 8; ++j) {
                float v = Wm[head * (C_ * D_) + (gg * 8 + j) * D_ + d];
                if (tau < 2) v *= qscale;
                wQKV[tau][j] = (_Float16)v;
            }
        }
    }
    // Wf^T A-frags for 16x16x16: A[row=c=ct*16+cc][k=f=kt*16+gg*4+j]
    f16x4 aWf[2][2];
    #pragma unroll
    for (int ct = 0; ct < 2; ++ct)
        #pragma unroll
        for (int kt = 0; kt < 2; ++kt)
            #pragma unroll
            for (int j = 0; j < 4; ++j)
                aWf[ct][kt][j] = (_Float16)Wf[(kt * 16 + gg * 4 + j) * C_ + ct * 16 + cc];
    // identity B-frag: I[k=gg*4+j][col=cc]
    f16x4 If;
    #pragma unroll
    for (int j = 0; j < 4; ++j)
        If[j] = (_Float16)((gg * 4 + j == cc) ? 1.0f : 0.0f);
    // bias per FF reg c = ct*16 + gg*4 + r
    const float4 ba = *(const float4*)(bfb + gg * 4);
    const float4 bbb = *(const float4*)(bfb + 16 + gg * 4);

    const int tilebase = (blockIdx.x * 4 + wid) * (16 * NT);
    const f32x4 z = { 0.f, 0.f, 0.f, 0.f };
    const bool gglo = (gg < 2);
    const f16x4 zero4 = { (_Float16)0, (_Float16)0, (_Float16)0, (_Float16)0 };

    // mask precompute: t = cc; s = gg*4+r. valid = same-batch && s<=t
    bool vmask[4];
    {
        const bool sb = ((gg >> 1) == (cc >> 3));
        #pragma unroll
        for (int r = 0; r < 4; ++r)
            vmask[r] = sb && (gg * 4 + r <= cc);
    }

    // rolling X prefetch (1 tile ahead)
    X2 x;
    {
        const float* p = X + (size_t)(tilebase + cc) * C_ + gg * 8;
        x.a = *(const float4*)p; x.b = *(const float4*)(p + 4);
    }

    #pragma unroll 1
    for (int it = 0; it < NT; ++it) {
        X2 xn;
        {
            const int itn = (it + 1 < NT) ? it + 1 : it;
            const float* p = X + (size_t)(tilebase + itn * 16 + cc) * C_ + gg * 8;
            xn.a = *(const float4*)p; xn.b = *(const float4*)(p + 4);
        }

        // X^T/X frag (works as B for transposed stage AND A for normal stage)
        f16x8 aX;
        aX[0] = (_Float16)x.a.x; aX[1] = (_Float16)x.a.y;
        aX[2] = (_Float16)x.a.z; aX[3] = (_Float16)x.a.w;
        aX[4] = (_Float16)x.b.x; aX[5] = (_Float16)x.b.y;
        aX[6] = (_Float16)x.b.z; aX[7] = (_Float16)x.b.w;

        // ---- stage: Q^T,K^T transposed; V normal (6 MFMAs) ----
        const f32x4 cq0 = __builtin_amdgcn_mfma_f32_16x16x32_f16(wQKV[0], aX, z, 0, 0, 0);
        const f32x4 cq1 = __builtin_amdgcn_mfma_f32_16x16x32_f16(wQKV[1], aX, z, 0, 0, 0);
        const f32x4 ck0 = __builtin_amdgcn_mfma_f32_16x16x32_f16(wQKV[2], aX, z, 0, 0, 0);
        const f32x4 ck1 = __builtin_amdgcn_mfma_f32_16x16x32_f16(wQKV[3], aX, z, 0, 0, 0);
        const f32x4 cv0 = __builtin_amdgcn_mfma_f32_16x16x32_f16(aX, wQKV[4], z, 0, 0, 0);
        const f32x4 cv1 = __builtin_amdgcn_mfma_f32_16x16x32_f16(aX, wQKV[5], z, 0, 0, 0);

        // cvt C-frags -> f16 chaining frags
        const f16x4 qT0 = mk4(cq0[0], cq0[1], cq0[2], cq0[3]);
        const f16x4 qT1 = mk4(cq1[0], cq1[1], cq1[2], cq1[3]);
        const f16x4 kT0 = mk4(ck0[0], ck0[1], ck0[2], ck0[3]);
        const f16x4 kT1 = mk4(ck1[0], ck1[1], ck1[2], ck1[3]);
        const f16x4 vF0 = mk4(cv0[0], cv0[1], cv0[2], cv0[3]);
        const f16x4 vF1 = mk4(cv1[0], cv1[1], cv1[2], cv1[3]);

        // per-head zeroed Q^T (k-range select by gg)
        const f16x4 qh0 = gglo ? qT0 : zero4;
        const f16x4 qh1 = gglo ? zero4 : qT0;
        const f16x4 qh2 = gglo ? qT1 : zero4;
        const f16x4 qh3 = gglo ? zero4 : qT1;

        // ---- scores: S^T_h[s][t] (s in regs, t in lane) ----
        const f32x4 s0 = __builtin_amdgcn_mfma_f32_16x16x16f16(kT0, qh0, z, 0, 0, 0);
        const f32x4 s1 = __builtin_amdgcn_mfma_f32_16x16x16f16(kT0, qh1, z, 0, 0, 0);
        const f32x4 s2 = __builtin_amdgcn_mfma_f32_16x16x16f16(kT1, qh2, z, 0, 0, 0);
        const f32x4 s3 = __builtin_amdgcn_mfma_f32_16x16x16f16(kT1, qh3, z, 0, 0, 0);

        // ---- mask + exp (no-max: scores O(0.1)) ----
        float e0[4], e1[4], e2[4], e3[4];
        #pragma unroll
        for (int r = 0; r < 4; ++r) {
            e0[r] = vmask[r] ? exp2f(s0[r]) : 0.f;
            e1[r] = vmask[r] ? exp2f(s1[r]) : 0.f;
            e2[r] = vmask[r] ? exp2f(s2[r]) : 0.f;
            e3[r] = vmask[r] ? exp2f(s3[r]) : 0.f;
        }
        // rowsum over s: local + xor16 + xor32 -> every lane holds sum(t=cc,h)
        float p0 = (e0[0] + e0[1]) + (e0[2] + e0[3]);
        float p1 = (e1[0] + e1[1]) + (e1[2] + e1[3]);
        float p2 = (e2[0] + e2[1]) + (e2[2] + e2[3]);
        float p3 = (e3[0] + e3[1]) + (e3[2] + e3[3]);
        p0 += __shfl_xor(p0, 16); p1 += __shfl_xor(p1, 16);
        p2 += __shfl_xor(p2, 16); p3 += __shfl_xor(p3, 16);
        p0 += __shfl_xor(p0, 32); p1 += __shfl_xor(p1, 32);
        p2 += __shfl_xor(p2, 32); p3 += __shfl_xor(p3, 32);
        const float w0 = 1.0f / p0, w1 = 1.0f / p1;
        const float w2 = 1.0f / p2, w3 = 1.0f / p3;

        // P^T f16 B-frags (unnormalized)
        const f16x4 P0 = mk4(e0[0], e0[1], e0[2], e0[3]);
        const f16x4 P1 = mk4(e1[0], e1[1], e1[2], e1[3]);
        const f16x4 P2 = mk4(e2[0], e2[1], e2[2], e2[3]);
        const f16x4 P3 = mk4(e3[0], e3[1], e3[2], e3[3]);

        // ---- PV: O^T_h[f'][t] (f' in regs, t in lane) ----
        const f32x4 o0 = __builtin_amdgcn_mfma_f32_16x16x16f16(vF0, P0, z, 0, 0, 0);
        const f32x4 o1 = __builtin_amdgcn_mfma_f32_16x16x16f16(vF0, P1, z, 0, 0, 0);
        const f32x4 o2 = __builtin_amdgcn_mfma_f32_16x16x16f16(vF1, P2, z, 0, 0, 0);
        const f32x4 o3 = __builtin_amdgcn_mfma_f32_16x16x16f16(vF1, P3, z, 0, 0, 0);

        // merge heads (valid rows: h even -> gg<2, h odd -> gg>=2) + scale
        const float wa = gglo ? w0 : w1;
        const float wb = gglo ? w2 : w3;
        f16x4 Bm0, Bm1;
        #pragma unroll
        for (int r = 0; r < 4; r += 2) {
            const float a0 = (gglo ? o0[r]     : o1[r])     * wa;
            const float a1 = (gglo ? o0[r + 1] : o1[r + 1]) * wa;
            const float b0 = (gglo ? o2[r]     : o3[r])     * wb;
            const float b1 = (gglo ? o2[r + 1] : o3[r + 1]) * wb;
            F4U t0, t1;
            t0.u[0] = pk(a0, a1); t1.u[0] = pk(b0, b1);
            if (r == 0) { Bm0[0] = t0.v[0]; Bm0[1] = t0.v[1]; Bm1[0] = t1.v[0]; Bm1[1] = t1.v[1]; }
            else        { Bm0[2] = t0.v[0]; Bm0[3] = t0.v[1]; Bm1[2] = t1.v[0]; Bm1[3] = t1.v[1]; }
        }

        // ---- FF: Y^T[c][t] = Wf^T O^T (2 c-tiles x 2 k-tiles) ----
        f32x4 yT0 = __builtin_amdgcn_mfma_f32_16x16x16f16(aWf[0][0], Bm0, z, 0, 0, 0);
        yT0 = __builtin_amdgcn_mfma_f32_16x16x16f16(aWf[0][1], Bm1, yT0, 0, 0, 0);
        f32x4 yT1 = __builtin_amdgcn_mfma_f32_16x16x16f16(aWf[1][0], Bm0, z, 0, 0, 0);
        yT1 = __builtin_amdgcn_mfma_f32_16x16x16f16(aWf[1][1], Bm1, yT1, 0, 0, 0);

        // bias + ReLU in Y^T layout (bias is per-reg here), then -> f16
        const f16x4 yf0 = mk4(fmaxf(yT0[0] + ba.x, 0.f), fmaxf(yT0[1] + ba.y, 0.f),
                              fmaxf(yT0[2] + ba.z, 0.f), fmaxf(yT0[3] + ba.w, 0.f));
        const f16x4 yf1 = mk4(fmaxf(yT1[0] + bbb.x, 0.f), fmaxf(yT1[1] + bbb.y, 0.f),
                              fmaxf(yT1[2] + bbb.z, 0.f), fmaxf(yT1[3] + bbb.w, 0.f));

        // transpose back via identity: Y[t][c] (t in regs, c in lane)
        const f32x4 yn0 = __builtin_amdgcn_mfma_f32_16x16x16f16(yf0, If, z, 0, 0, 0);
        const f32x4 yn1 = __builtin_amdgcn_mfma_f32_16x16x16f16(yf1, If, z, 0, 0, 0);

        // coalesced NON-TEMPORAL stores: Y never re-read -> keep out of L2/L3
        const int rowbase = tilebase + it * 16;
        #pragma unroll
        for (int r = 0; r < 4; ++r) {
            float* yp = Y + (size_t)(rowbase + gg * 4 + r) * C_;
            __builtin_nontemporal_store(yn0[r], yp + cc);
            __builtin_nontemporal_store(yn1[r], yp + cc + 16);
        }

        x = xn;
    }
}

extern "C" void kernel_launch(void* const* d_in, const int* in_sizes, int n_in,
                              void* d_out, int out_size, void* d_ws, size_t ws_size,
                              hipStream_t stream)
{
    const float* X  = (const float*)d_in[0];
    const float* Wq = (const float*)d_in[1];
    const float* Wk = (const float*)d_in[2];
    const float* Wv = (const float*)d_in[3];
    const float* Wf = (const float*)d_in[4];
    const float* bf = (const float*)d_in[5];
    float* Y = (float*)d_out;

    const int rows = B_ * T_;                 // 1,048,576
    const int rows_per_block = 4 * NT * 16;   // 256
    dim3 grid(rows / rows_per_block), block(256);
    hipLaunchKernelGGL(attn_block_mfma, grid, block, 0, stream,
                       X, Wq, Wk, Wv, Wf, bf, Y);
}